// Round 11
// baseline (66.312 us; speedup 1.0000x reference)
//
#include <hip/hip_runtime.h>

// Dist_Conv2D_Dense: Chebyshev (L-inf) distance "conv".
// B=8, Cin=16, H=W=64, Cout=32, K=3, stride=1, edge-replicate pad.
// out[b][co][h][w] = max_{cin,kh,kw} |x[b][cin][clamp(h+kh-1)][clamp(w+kw-1)]
//                                    - wt[co][cin][kh][kw]|  + bias[co]
//
// Round-11: software-pipelined cin loop. Evidence: warm kernel 12.1us @
// VALUBusy 53% (stall ~47%), VGPR=36 -> compiler keeps only ~9 loads in
// flight, so each of 16 cin steps eats L1/L2 (~200cy) or cold-HBM (~900cy)
// latency. Fix: 4-cin groups, 2-deep double buffer (load group g+1 while
// computing group g) -> 36 outstanding loads, ~90 VGPR (<128 cap).
// Structure else identical to round-7/8 (1 px x 4 couts, 1024 blocks).

constexpr int Bn = 8, Cin = 16, Hn = 64, Wn = 64, Cout = 32;
constexpr int CPT = 4;            // couts per thread
constexpr int NG  = Cout / CPT;   // 8 cout groups
constexpr int BLOCK = 256;
constexpr int CG = 4;             // cin group size

__global__ __launch_bounds__(BLOCK, 4)   // <=128 VGPR -> 4 blocks/CU with 1024-block grid
void dist_conv_kernel(const float* __restrict__ x,
                      const float* __restrict__ wt,
                      const float* __restrict__ bias,
                      float* __restrict__ out) {
    __shared__ float4 wl[Cin * 9];

    const int g    = blockIdx.x >> 7;         // cout group 0..7
    const int pblk = blockIdx.x & 127;        // pixel block 0..127

    // Stage weights: [cin][k] -> float4 over 4 couts
    for (int i = threadIdx.x; i < Cin * 9 * CPT; i += BLOCK) {
        const int cin = i / (9 * CPT);
        const int rem = i % (9 * CPT);
        const int k   = rem / CPT;
        const int c   = rem % CPT;
        reinterpret_cast<float*>(wl)[(cin * 9 + k) * CPT + c] =
            wt[((g * CPT + c) * Cin + cin) * 9 + k];
    }
    __syncthreads();

    const int p  = pblk * BLOCK + threadIdx.x;    // 0..32767
    const int w0 = p & 63;
    const int h  = (p >> 6) & 63;
    const int b  = p >> 12;

    const int hm = max(h - 1, 0) * Wn;
    const int h0 = h * Wn;
    const int hp = min(h + 1, Hn - 1) * Wn;
    const int cm = max(w0 - 1, 0);
    const int cp = min(w0 + 1, Wn - 1);

    float acc[CPT] = {0.f, 0.f, 0.f, 0.f};
    const float* xb = x + b * (Cin * Hn * Wn);

    // Load 4 cins' 3x3 windows into a named register buffer.
    auto loadG = [&](float (&xr)[CG][3][3], int cin0) {
#pragma unroll
        for (int q = 0; q < CG; ++q) {
            const float* xc = xb + (cin0 + q) * (Hn * Wn);
            xr[q][0][0] = xc[hm + cm]; xr[q][0][1] = xc[hm + w0]; xr[q][0][2] = xc[hm + cp];
            xr[q][1][0] = xc[h0 + cm]; xr[q][1][1] = xc[h0 + w0]; xr[q][1][2] = xc[h0 + cp];
            xr[q][2][0] = xc[hp + cm]; xr[q][2][1] = xc[hp + w0]; xr[q][2][2] = xc[hp + cp];
        }
    };
    // Consume 4 cins: 9 taps x 4 couts each, exact f32.
    auto compG = [&](const float (&xr)[CG][3][3], int cin0) {
#pragma unroll
        for (int q = 0; q < CG; ++q) {
#pragma unroll
            for (int kh = 0; kh < 3; ++kh) {
#pragma unroll
                for (int kw = 0; kw < 3; ++kw) {
                    const float4 wv = wl[(cin0 + q) * 9 + kh * 3 + kw];
                    const float xa = xr[q][kh][kw];
                    acc[0] = fmaxf(acc[0], fabsf(xa - wv.x));
                    acc[1] = fmaxf(acc[1], fabsf(xa - wv.y));
                    acc[2] = fmaxf(acc[2], fabsf(xa - wv.z));
                    acc[3] = fmaxf(acc[3], fabsf(xa - wv.w));
                }
            }
        }
    };

    float A[CG][3][3], Bf[CG][3][3];
    loadG(A, 0);
    loadG(Bf, 4);   compG(A, 0);     // loads for 4..7 in flight over compute of 0..3
    loadG(A, 8);    compG(Bf, 4);
    loadG(Bf, 12);  compG(A, 8);
    compG(Bf, 12);

    float* ob = out + b * (Cout * Hn * Wn) + h0 + w0;
#pragma unroll
    for (int c = 0; c < CPT; ++c) {
        const int co = g * CPT + c;
        ob[co * (Hn * Wn)] = acc[c] + bias[co];
    }
}

extern "C" void kernel_launch(void* const* d_in, const int* in_sizes, int n_in,
                              void* d_out, int out_size, void* d_ws, size_t ws_size,
                              hipStream_t stream) {
    const float* x    = (const float*)d_in[0];
    const float* wt   = (const float*)d_in[1];
    const float* bias = (const float*)d_in[2];
    float* out        = (float*)d_out;

    const int pixels = Bn * Hn * Wn;               // 32768
    const int grid   = NG * (pixels / BLOCK);      // 1024
    dist_conv_kernel<<<grid, BLOCK, 0, stream>>>(x, wt, bias, out);
}